// Round 6
// baseline (341.149 us; speedup 1.0000x reference)
//
#include <hip/hip_runtime.h>

// ---------------------------------------------------------------------------
// CCALayer: spt (1,5,640,10,10)  qry (75,640,10,10)
// Q=75, way=5, C=640, Cf=64, P=100 (10x10), items=375
// Output: sim (75,5) [375] ++ qry_pooled (75,640) [48000]
// ---------------------------------------------------------------------------

#define NITEM 375

// ws layout (float offsets)
#define OFF_XTS 0            // raw support transposed fp16 [5][100 p][640 c]
#define OFF_XTQ 160000       // raw query transposed fp16 [75][100][640]
#define OFF_MP  2560000      // per-image position means [80][100] f32
#define OFF_SF  2568000      // support feature MFMA frags fp16 [5][14336B]
#define OFF_QF  2600000      // query feature MFMA frags fp16 [75][14336B]
#define OFF_RA  3080000      // branch-A result 375*10000
#define OFF_RB  6830000      // branch-B result 375*10000
#define OFF_PRM 10655000     // folded params

#define PK2F 232
#define PK1F 1512
#define WSUMF 2792
#define SCVF 2856
#define SHVF 2920
#define PKWF 2984

// k_cca LDS byte map (dynamic, 154688 total). R10: Y1 eliminated — loop1
// reconstructs its rank-1 B-operand from T2 scalars on the fly.
//   T2 region [0,26600): 12 slices (s' = f1+1, rows -1..10) x 2000B interior
//     at 200 + s'*2200; 200B guard gaps before each slice + trailing guard.
//     Pads + slices 0,11 hold fp16 NaN (0x7E00): conv-OOB taps read NaN and
//     relu(Av*NaN+Bp) = fmaxf(NaN,0) = 0 -> zero contribution, maskless.
//   ZPB5 [26608,26624): 16B f32 zero page for loop2 masked reads.
//   T1   [26688,90688): [f(100)][s1(10)][16] f32 (64B rows)
//   CORR [90688,154688): same layout
//   Y2   [26688,58944): overlays T1 (dead in main loop); 2 ch-halves x 16128B
#define T2GAP    200
#define T2SSTR   2200
#define T2INT0   2400        // slice s'=1 (f1=0) interior base = 200 + 2200
#define ZPB5     26608
#define T1B      26688
#define CORRB    90688
#define Y2S5     26688
#define Y2HH     16128
#define LDS_TOTAL5 154688

typedef float f4v __attribute__((ext_vector_type(4)));
typedef float f32x4 __attribute__((ext_vector_type(4)));
typedef _Float16 half8v __attribute__((ext_vector_type(8)));
typedef __fp16 fp16x2 __attribute__((ext_vector_type(2)));
typedef unsigned int u32x4 __attribute__((ext_vector_type(4)));
typedef unsigned int u32x2 __attribute__((ext_vector_type(2)));

__device__ __forceinline__ unsigned int pkrtz(float a, float b) {
  union { fp16x2 h; unsigned int u; } cv;
  cv.h = __builtin_amdgcn_cvt_pkrtz(a, b);
  return cv.u;
}

// ---------------------------------------------------------------------------
// Merged param-folding kernel. grid = 65 blocks.
__global__ __launch_bounds__(256) void k_prep(
    const float* __restrict__ w1x1,  const float* __restrict__ bn1x1,
    const float* __restrict__ c1c2w, const float* __restrict__ c1bn2,
    const float* __restrict__ c1c1w, const float* __restrict__ c1bn1,
    const float* __restrict__ c1pj,  const float* __restrict__ c1bnp,
    const float* __restrict__ c2c2w, const float* __restrict__ c2bn2,
    const float* __restrict__ c2c1w, const float* __restrict__ c2bn1,
    const float* __restrict__ c2pj,  const float* __restrict__ c2bnp,
    float* __restrict__ prm)
{
  const int t = threadIdx.x;
  const float eps = 1e-5f;

  if (blockIdx.x < 64) {
    __shared__ float red[4];
    _Float16* pkw = (_Float16*)(prm + PKWF);
    const int base = blockIdx.x * 800;
    for (int r = t; r < 800; r += 256) {
      int idx = base + r;
      int fi = idx >> 9, rem = idx & 511;
      int ln = rem >> 3, j = rem & 7;
      int cc = fi / 10, r2 = fi - cc * 10;
      int mt = r2 >> 1, kk = r2 & 1;
      int m = mt * 16 + (ln & 15);
      int k = cc * 64 + kk * 32 + ((ln >> 4) & 3) * 8 + j;
      float v = (m < 64) ? w1x1[m * 640 + k] : (m == 64 ? 1.f : 0.f);
      pkw[idx] = (_Float16)v;
    }
    const int o = blockIdx.x;
    float s = 0.f;
    for (int c = t; c < 640; c += 256) s += w1x1[o * 640 + c];
    #pragma unroll
    for (int off = 32; off > 0; off >>= 1) s += __shfl_down(s, off);
    if ((t & 63) == 0) red[t >> 6] = s;
    __syncthreads();
    if (t == 0) {
      prm[WSUMF + o] = red[0] + red[1] + red[2] + red[3];
      float scv = bn1x1[o] / sqrtf(bn1x1[192 + o] + eps);
      prm[SCVF + o] = scv;
      prm[SHVF + o] = bn1x1[64 + o] - bn1x1[128 + o] * scv;
    }
    return;
  }

  for (int idx = t; idx < 144; idx += 256) {
    int ds = idx / 16, i = idx % 16;
    float spv = c2bnp[0] / sqrtf(c2bnp[3] + eps);
    float acc = 0.f;
    for (int o = 0; o < 16; ++o) {
      float s1 = c2bn1[o] / sqrtf(c2bn1[48 + o] + eps);
      acc += c2pj[o] * s1 * c2c1w[(o * 16 + i) * 9 + ds];
    }
    prm[idx] = spv * acc;
  }
  for (int i = t; i < 16; i += 256) {
    float s = c1bnp[i] / sqrtf(c1bnp[48 + i] + eps);
    prm[144 + i] = s * c1pj[i];
    prm[160 + i] = c1bnp[16 + i] - c1bnp[32 + i] * s;
  }
  for (int o = t; o < 16; o += 256) {
    float s = c2bn2[o] / sqrtf(c2bn2[48 + o] + eps);
    prm[176 + o] = s;
    prm[192 + o] = c2bn2[16 + o] - c2bn2[32 + o] * s;
  }
  for (int k = t; k < 9; k += 256) {
    prm[208 + k] = c1c2w[k];
    prm[217 + k] = c1c1w[k];
  }
  if (t == 0) {
    float S2 = c1bn2[0] / sqrtf(c1bn2[3] + eps);
    prm[226] = S2;
    prm[227] = c1bn2[1] - c1bn2[2] * S2;
    float S1 = c1bn1[0] / sqrtf(c1bn1[3] + eps);
    prm[228] = S1;
    prm[229] = c1bn1[1] - c1bn1[2] * S1;
    float spv = c2bnp[0] / sqrtf(c2bnp[3] + eps);
    float k0 = 0.f;
    for (int o = 0; o < 16; ++o) {
      float s1 = c2bn1[o] / sqrtf(c2bn1[48 + o] + eps);
      k0 += c2pj[o] * (c2bn1[16 + o] - c2bn1[32 + o] * s1);
    }
    prm[230] = spv * (k0 - c2bnp[2]) + c2bnp[1];
    prm[231] = 0.f;
  }
  __syncthreads();

  _Float16* pk2 = (_Float16*)(prm + PK2F);
  for (int idx = t; idx < 2560; idx += 256) {
    int c = idx >> 9, rem = idx & 511;
    int ln = rem >> 3, j = rem & 7;
    int o = ln & 15, qq = ln >> 4;
    int tap = 2 * c + (qq >> 1);
    int i = (qq & 1) * 8 + j;
    float v = (tap < 9) ? c2c2w[(o * 16 + i) * 9 + tap] : 0.f;
    pk2[idx] = (_Float16)v;
  }
  _Float16* pk1 = (_Float16*)(prm + PK1F);
  for (int idx = t; idx < 2560; idx += 256) {
    int c = idx >> 9, rem = idx & 511;
    int ln = rem >> 3, j = rem & 7;
    int m = ln & 15, qq = ln >> 4;
    int k = c * 32 + qq * 8 + j;
    int tp = k >> 4, i = k & 15;
    float v = (m == 0 && tp < 9) ? prm[tp * 16 + i] : 0.f;
    pk1[idx] = (_Float16)v;
  }
}

// ---------------------------------------------------------------------------
// Fused center + 1x1 conv (MFMA) + BN + relu + L2 norm + XT emit + qry_pooled.
__global__ __launch_bounds__(512) void k_feat(
    const float* __restrict__ spt, const float* __restrict__ qry,
    float* __restrict__ ws, float* __restrict__ out)
{
  __shared__ __align__(16) char POOL[2 * 16128];   // XTL[2]; OUT overlays
  __shared__ __align__(16) float mrow[112];
  __shared__ __align__(16) float rn[112];
  __shared__ float CS[2][512];
  __shared__ float RS[640];
  __shared__ float msumL;

  const int b = blockIdx.x, t = threadIdx.x;
  const int lane = t & 63, wvv = t >> 6;             // 8 waves
  const int n0 = lane & 15, qd = (lane >> 4) & 3;
  const float* src = (b < 5) ? spt + b * 64000 : qry + (b - 5) * 64000;
  unsigned int* xtg = (unsigned int*)(ws + ((b < 5) ? (OFF_XTS + b * 32000)
                                                    : (OFF_XTQ + (b - 5) * 32000)));
  const float* prm = ws + OFF_PRM;
  const _Float16* pkw = (const _Float16*)(prm + PKWF);

  for (int idx = t; idx < 864; idx += 512) {
    int bsel = idx / 432, r = idx - bsel * 432;
    ((unsigned int*)(POOL + bsel * 16128 + 100 * 144))[r] = 0u;
  }
  for (int u = t; u < 800; u += 512) {
    int cp = u / 25, p4 = u - cp * 25;
    const float* r0 = src + (2 * cp) * 100 + p4 * 4;
    f4v a = *(const f4v*)r0;
    f4v c1 = *(const f4v*)(r0 + 100);
    #pragma unroll
    for (int e = 0; e < 4; ++e)
      *(unsigned int*)((_Float16*)POOL + (p4 * 4 + e) * 72 + 2 * cp) = pkrtz(a[e], c1[e]);
  }
  __syncthreads();

  const int chp = t >> 3, part = t & 7;
  const int pLo = part * 13, pHi = (pLo + 13 < 100) ? pLo + 13 : 100;

  f32x4 acc[5];
  #pragma unroll
  for (int ti = 0; ti < 5; ++ti) { acc[ti][0]=0.f; acc[ti][1]=0.f; acc[ti][2]=0.f; acc[ti][3]=0.f; }

  for (int cc = 0; cc < 10; ++cc) {
    const int cur = cc & 1;
    const _Float16* Xc = (const _Float16*)(POOL + cur * 16128);
    _Float16* Xn = (_Float16*)(POOL + (cur ^ 1) * 16128);

    f4v pa[2], pc[2];
    if (cc < 9) {
      #pragma unroll
      for (int k = 0; k < 2; ++k) {
        int u = t + k * 512;
        if (u < 800) {
          int cp = u / 25, p4 = u - cp * 25;
          const float* r0 = src + ((cc + 1) * 64 + 2 * cp) * 100 + p4 * 4;
          pa[k] = *(const f4v*)r0;
          pc[k] = *(const f4v*)(r0 + 100);
        }
      }
    }
    for (int u = t; u < 3200; u += 512) {
      int p = u >> 5, cp = u & 31;
      xtg[p * 320 + cc * 32 + cp] = *(const unsigned int*)(Xc + p * 72 + 2 * cp);
    }
    #pragma unroll
    for (int kk = 0; kk < 2; ++kk) {
      #pragma unroll
      for (int ti = 0; ti < 5; ++ti) {
        int idx = wvv + ti * 8; if (idx > 34) idx = 34;
        int mt = idx / 7, nt = idx - mt * 7;
        half8v av = *(const half8v*)(pkw + (cc * 10 + mt * 2 + kk) * 512 + lane * 8);
        half8v bv = *(const half8v*)(Xc + (nt * 16 + n0) * 72 + kk * 32 + qd * 8);
        acc[ti] = __builtin_amdgcn_mfma_f32_16x16x32_f16(av, bv, acc[ti], 0, 0, 0);
      }
    }
    {
      float s = 0.f;
      for (int p = pLo; p < pHi; ++p) s += (float)Xc[p * 72 + chp];
      CS[cur][t] = s;
    }
    if (cc < 9) {
      #pragma unroll
      for (int k = 0; k < 2; ++k) {
        int u = t + k * 512;
        if (u < 800) {
          int cp = u / 25, p4 = u - cp * 25;
          #pragma unroll
          for (int e = 0; e < 4; ++e)
            *(unsigned int*)(Xn + (p4 * 4 + e) * 72 + 2 * cp) = pkrtz(pa[k][e], pc[k][e]);
        }
      }
    }
    __syncthreads();
    if (t < 64) {
      float s = 0.f;
      #pragma unroll
      for (int k = 0; k < 8; ++k) s += CS[cur][t * 8 + k];
      RS[cc * 64 + t] = s;
    }
  }
  #pragma unroll
  for (int ti = 0; ti < 5; ++ti) {
    int idx = wvv + ti * 8; if (idx > 34) idx = 34;
    int mt = idx / 7, nt = idx - mt * 7;
    if (mt == 4 && qd == 0) {
      int p = nt * 16 + n0;
      mrow[p] = acc[ti][0] * (1.f / 640.f);
    }
  }
  __syncthreads();
  float* OUT = (float*)POOL;                 // overlay: XTL dead from here
  if (t == 0) { float s = 0.f; for (int p = 0; p < 100; ++p) s += mrow[p]; msumL = s; }
  #pragma unroll
  for (int ti = 0; ti < 5; ++ti) {
    int idx = wvv + ti * 8; if (idx > 34) idx = 34;
    int mt = idx / 7, nt = idx - mt * 7;
    if (mt < 4) {
      int p = nt * 16 + n0;
      if (p < 100) {
        float mp = mrow[p];
        #pragma unroll
        for (int r = 0; r < 4; ++r) {
          int o = mt * 16 + qd * 4 + r;
          float v = acc[ti][r] - prm[WSUMF + o] * mp;
          v = prm[SCVF + o] * v + prm[SHVF + o];
          OUT[o * 104 + p] = v > 0.f ? v : 0.f;
        }
      }
    }
  }
  __syncthreads();
  if (t < 100) {
    float s = 0.f;
    for (int o = 0; o < 64; ++o) { float v = OUT[o * 104 + t]; s += v * v; }
    float nr = sqrtf(s);
    rn[t] = 1.f / (nr > 1e-8f ? nr : 1e-8f);
    ws[OFF_MP + b * 100 + t] = mrow[t];
  }
  __syncthreads();
  {
    unsigned int* fg = (unsigned int*)((b < 5) ? (ws + OFF_SF) : (ws + OFF_QF))
                       + ((b < 5) ? b : (b - 5)) * 3584;
    for (int idx = t; idx < 3584; idx += 512) {
      const int jj = idx & 3;
      const int ln2 = (idx >> 2) & 63;
      const int fi = idx >> 8;
      const int kk = fi / 7, pt = fi - kk * 7;
      const int pos = pt * 16 + (ln2 & 15);
      const int c0 = kk * 32 + ((ln2 >> 4) & 3) * 8 + 2 * jj;
      float a = 0.f, bb = 0.f;
      if (pos < 100) {
        const float rv = rn[pos];
        a = OUT[c0 * 104 + pos] * rv;
        bb = OUT[(c0 + 1) * 104 + pos] * rv;
      }
      fg[idx] = pkrtz(a, bb);
    }
  }
  if (b >= 5) {
    const float msum = msumL;
    for (int gc = t; gc < 640; gc += 512)
      out[375 + (b - 5) * 640 + gc] = (RS[gc] - msum) * 0.01f;
  }
}

// ---------------------------------------------------------------------------
// Fused corr + cca branch. grid = 375 items x 2 branches.
// R10: loop1's B-operand reconstructed on the fly from T2 scalars
// (y1[ch] = relu(Av[ch]*t2 + Bp[ch]), rank-1) -> Y1 region, GEN_Y1 and slot
// rotation deleted; OOB taps read NaN pads (fmaxf(NaN,0)=0, maskless).
__global__ __launch_bounds__(1024) __attribute__((amdgpu_waves_per_eu(4, 4)))
void k_cca(float* __restrict__ ws)
{
  extern __shared__ char smem[];
  float* T1   = (float*)(smem + T1B);
  float* CORR = (float*)(smem + CORRB);

  const float* prm = ws + OFF_PRM;
  const int bid = blockIdx.x;
  const int it = bid >> 1, br = bid & 1;
  const int q = it / 5, n = it % 5;
  const int t = threadIdx.x;
  const int lane = t & 63, wv = t >> 6;
  const int n0 = lane & 15, qd = (lane >> 4) & 3;
  const int qh = qd >> 1, ih = qd & 1;

  const _Float16* pk2 = (const _Float16*)(prm + PK2F);
  const _Float16* pk1 = (const _Float16*)(prm + PK1F);
  half8v A2[5], A1[5];
  #pragma unroll
  for (int c = 0; c < 5; ++c) {
    A2[c] = *(const half8v*)(pk2 + c * 512 + lane * 8);
    A1[c] = *(const half8v*)(pk1 + c * 512 + lane * 8);
  }
  float sc2[4], bc2[4];
  #pragma unroll
  for (int r = 0; r < 4; ++r) { sc2[r] = prm[176 + qd * 4 + r]; bc2[r] = prm[192 + qd * 4 + r]; }

  // per-lane channel-half affine params for Y1 reconstruction
  float AvL[8], BpL[8];
  #pragma unroll
  for (int j = 0; j < 8; ++j) {
    AvL[j] = prm[144 + ih * 8 + j];
    BpL[j] = prm[160 + ih * 8 + j];
  }

  const int d1E[5] = {-1,-1, 0, 0, 1}, d2E[5] = {-1, 1, 0,-1, 1};
  const int d1O[5] = {-1, 0, 0, 1, 0}, d2O[5] = { 0,-1, 1, 0, 0};

  // ---- g-invariant per-tile precompute ----
  int pos2[4], st1[4], addr2[4][5], posB[4], D1F[5];
  bool pv[4];
  #pragma unroll
  for (int c = 0; c < 5; ++c) {
    const int d1 = qh ? d1O[c] : d1E[c];
    const int d2 = qh ? d2O[c] : d2E[c];
    D1F[c] = d1 * T2SSTR + d2 * 200;     // slice step + (100 pos * 2B) col step
  }
  #pragma unroll
  for (int ti = 0; ti < 4; ++ti) {
    int tile = wv + ti * 16; if (tile > 62) tile = 62;
    const int p = tile * 16 + n0;
    const int pcp = p < 1000 ? p : 999;
    pos2[ti] = pcp * 2;
    st1[ti] = Y2S5 + qh * Y2HH + p * 16 + ih * 8;
    pv[ti] = (qd == 0) && (p < 1000);
    const int f2 = pcp / 100;
    const int s = pcp - f2 * 100;
    const int s1 = s / 10, s2 = s - s1 * 10;
    const bool rm = s1 > 0, rp = s1 < 9, cm = s2 > 0, cp2 = s2 < 9;
    const int b0 = Y2S5 + ih * Y2HH + pcp * 16;
    #pragma unroll
    for (int c = 0; c < 5; ++c) {
      const bool vE = (d1E[c] < 0 ? rm : (d1E[c] > 0 ? rp : true)) &&
                      (d2E[c] < 0 ? cm : (d2E[c] > 0 ? cp2 : true));
      const bool vO = (c == 4) ? false :
                      ((d1O[c] < 0 ? rm : (d1O[c] > 0 ? rp : true)) &&
                       (d2O[c] < 0 ? cm : (d2O[c] > 0 ? cp2 : true)));
      const bool v = qh ? vO : vE;
      const int D1c = (qh ? (d1O[c] * 10 + d2O[c]) : (d1E[c] * 10 + d2E[c]));
      addr2[ti][c] = v ? (b0 + D1c * 16) : ZPB5;
    }
    posB[ti] = br ? (s * 100 + f2) : (f2 * 100 + s);
  }
  const int posStride = br ? 10 : 1000;

  // ---- phase B: corr via MFMA from fp16 frags in global (L2-hot) ----
  {
    const half8v* fS = (const half8v*)(ws + OFF_SF) + n * 896;
    const half8v* fQ = (const half8v*)(ws + OFF_QF) + q * 896;
    const half8v* FA = br ? fQ : fS;   // rows (conv-f axis)
    const half8v* FB = br ? fS : fQ;   // cols (s axis)
    #pragma unroll
    for (int ti = 0; ti < 4; ++ti) {
      int T = wv + ti * 16; if (T > 48) T = 48;
      const int mt = T / 7, nt = T - mt * 7;
      half8v a0 = FA[mt * 64 + lane];
      half8v b0 = FB[nt * 64 + lane];
      half8v a1 = FA[(7 + mt) * 64 + lane];
      half8v b1 = FB[(7 + nt) * 64 + lane];
      f32x4 acc; acc[0]=0.f; acc[1]=0.f; acc[2]=0.f; acc[3]=0.f;
      acc = __builtin_amdgcn_mfma_f32_16x16x32_f16(a0, b0, acc, 0, 0, 0);
      acc = __builtin_amdgcn_mfma_f32_16x16x32_f16(a1, b1, acc, 0, 0, 0);
      const int s = nt * 16 + n0;
      if (s < 100) {
        const int s1a = s / 10;
        float* cp0 = CORR + s1a * 16 + (s - s1a * 10);
        const int r0 = mt * 16 + qd * 4;
        #pragma unroll
        for (int r = 0; r < 4; ++r)
          if (r0 + r < 100) cp0[(r0 + r) * 160] = acc[r];
      }
    }
  }
  __syncthreads();

  const float S2 = prm[226], B2 = prm[227], S1 = prm[228], B1 = prm[229];

  // ---- phase C: conv2-stage (3x3 over f), register-blocked over f1;
  //      threads t>=600 fill T2 pads with fp16 NaN + zero the ZPB5 page ----
  if (t < 600) {
    const int h = t / 300, r2 = t - h * 300;
    const int f2 = r2 / 30, r3 = r2 - f2 * 30;
    const int s1v = r3 / 3, s2q = r3 - s1v * 3;
    const int cb = s1v * 16 + s2q * 4;
    f4v outv[5];
    #pragma unroll
    for (int i = 0; i < 5; ++i) { outv[i][0]=0.f; outv[i][1]=0.f; outv[i][2]=0.f; outv[i][3]=0.f; }
    #pragma unroll
    for (int k = 0; k < 7; ++k) {
      const int nf1 = 5 * h - 1 + k;
      if ((unsigned)nf1 >= 10u) continue;
      #pragma unroll
      for (int dv = 0; dv < 3; ++dv) {
        const int nf2 = f2 + dv - 1;
        if ((unsigned)nf2 >= 10u) continue;
        f4v x = *(const f4v*)(CORR + (nf1 * 10 + nf2) * 160 + cb);
        #pragma unroll
        for (int du = 0; du < 3; ++du) {
          const int f1l = k - du;
          if (f1l < 0 || f1l > 4) continue;
          const float w = prm[208 + du * 3 + dv];
          #pragma unroll
          for (int e = 0; e < 4; ++e) outv[f1l][e] += w * x[e];
        }
      }
    }
    #pragma unroll
    for (int f1l = 0; f1l < 5; ++f1l) {
      const int f = (5 * h + f1l) * 10 + f2;
      f4v v;
      #pragma unroll
      for (int e = 0; e < 4; ++e) { float z = S2 * outv[f1l][e] + B2; v[e] = z > 0.f ? z : 0.f; }
      *(f4v*)(T1 + f * 160 + cb) = v;
    }
  } else {
    // NaN-fill: gaps s'=0..11, slice 0 (row -1), slice 11 (row 10), trail.
    const unsigned NN = 0x7E007E00u;
    for (int z = t - 600; z < 1650; z += 424) {
      int addr;
      if (z < 550) addr = z * 4;                                // [0,2200)
      else if (z < 1100) addr = 24400 + (z - 550) * 4;          // [24400,26600)
      else { int k = z - 1100; int gi = k / 50 + 1; addr = gi * T2SSTR + (k - (gi - 1) * 50) * 4; }
      *(unsigned*)(smem + addr) = NN;
    }
    if (t - 600 < 4) *(unsigned*)(smem + ZPB5 + (t - 600) * 4) = 0u;
  }
  __syncthreads();

  // ---- phase D: conv1-stage (3x3 over s) per f-row -> padded T2 (fp16) ----
  if (t < 1000) {
    const int f = t / 10, s1 = t - (t / 10) * 10;
    const float* rowB = T1 + f * 160;
    f4v r[3][3];
    float w[3][3];
    #pragma unroll
    for (int dh = 0; dh < 3; ++dh) {
      int rr = s1 + dh - 1;
      bool okr = (unsigned)rr < 10u;
      int rc = rr < 0 ? 0 : (rr > 9 ? 9 : rr);
      const float* rp = rowB + rc * 16;
      r[dh][0] = *(const f4v*)(rp);
      r[dh][1] = *(const f4v*)(rp + 4);
      r[dh][2] = *(const f4v*)(rp + 8);
      #pragma unroll
      for (int dw = 0; dw < 3; ++dw) w[dh][dw] = okr ? prm[217 + dh * 3 + dw] : 0.f;
    }
    float o[10];
    #pragma unroll
    for (int s2 = 0; s2 < 10; ++s2) {
      float a = 0.f;
      #pragma unroll
      for (int dh = 0; dh < 3; ++dh)
        #pragma unroll
        for (int dw = 0; dw < 3; ++dw) {
          int col = s2 + dw - 1;
          if (col < 0 || col > 9) continue;
          a += w[dh][dw] * r[dh][col >> 2][col & 3];
        }
      o[s2] = a;
    }
    const int f1 = f / 10, f2 = f - f1 * 10;
    unsigned int* dst = (unsigned int*)(smem + T2INT0 + f1 * T2SSTR + (f2 * 100 + s1 * 10) * 2);
    #pragma unroll
    for (int k = 0; k < 5; ++k)
      dst[k] = pkrtz(S1 * o[2 * k] + B1, S1 * o[2 * k + 1] + B1);
  }
  __syncthreads();

  const float Cf = prm[230];
  float* resb = ws + (br ? OFF_RB : OFF_RA) + it * 10000;
  int gp = 0;

  for (int g = 0; g < 10; ++g) {
    const int gB = T2INT0 + g * T2SSTR;   // slice s' = g+1 interior base

    // loop1: conv2 over (f1,f2) via MFMA; B built from T2 scalars
    #pragma unroll
    for (int ti = 0; ti < 4; ++ti) {
      f32x4 acc; acc[0]=0.f; acc[1]=0.f; acc[2]=0.f; acc[3]=0.f;
      #pragma unroll
      for (int c = 0; c < 5; ++c) {
        const int ad = gB + D1F[c] + pos2[ti];
        const float t2f = (float)(*(const __fp16*)(smem + ad));
        union { u32x4 u; half8v h; } bb;
        #pragma unroll
        for (int jj = 0; jj < 4; ++jj)
          bb.u[jj] = pkrtz(fmaxf(AvL[2 * jj] * t2f + BpL[2 * jj], 0.f),
                           fmaxf(AvL[2 * jj + 1] * t2f + BpL[2 * jj + 1], 0.f));
        acc = __builtin_amdgcn_mfma_f32_16x16x32_f16(A2[c], bb.h, acc, 0, 0, 0);
      }
      const float v0 = fmaxf(sc2[0] * acc[0] + bc2[0], 0.f);
      const float v1 = fmaxf(sc2[1] * acc[1] + bc2[1], 0.f);
      const float v2 = fmaxf(sc2[2] * acc[2] + bc2[2], 0.f);
      const float v3 = fmaxf(sc2[3] * acc[3] + bc2[3], 0.f);
      u32x2 wq; wq[0] = pkrtz(v0, v1); wq[1] = pkrtz(v2, v3);
      *(u32x2*)(smem + st1[ti]) = wq;
    }
    __syncthreads();

    // loop2: conv1eff over (s1,s2) via MFMA on Y2
    #pragma unroll
    for (int ti = 0; ti < 4; ++ti) {
      f32x4 acc; acc[0]=0.f; acc[1]=0.f; acc[2]=0.f; acc[3]=0.f;
      #pragma unroll
      for (int c = 0; c < 5; ++c) {
        half8v b = *(const half8v*)(smem + addr2[ti][c]);
        acc = __builtin_amdgcn_mfma_f32_16x16x32_f16(A1[c], b, acc, 0, 0, 0);
      }
      if (pv[ti]) resb[posB[ti] + gp] = acc[0] + Cf;
    }
    gp += posStride;
    __syncthreads();
  }
}

// ---------------------------------------------------------------------------
// Fused stats (gaussian_normalize + softmax + attn sums) + attention pooling
// + cosine similarity. grid = 375 items.
__global__ __launch_bounds__(256) void k_post(float* __restrict__ ws,
                                              float* __restrict__ out)
{
  __shared__ float F[10000];
  __shared__ float mc[100], ic[100], rc[100];
  __shared__ float mr[100], ir[100], rr[100];
  __shared__ float asL[100], aqL[100], msL[100], mqL[100];
  __shared__ float alph[2];
  __shared__ float red[12];
  const int it = blockIdx.x, t = threadIdx.x;
  const int q = it / 5, n = it % 5;

  const f4v* ra4 = (const f4v*)(ws + OFF_RA + it * 10000);
  const f4v* rb4 = (const f4v*)(ws + OFF_RB + it * 10000);
  f4v* F4 = (f4v*)F;
  for (int idx = t; idx < 2500; idx += 256) {
    f4v a = ra4[idx], b = rb4[idx];
    #pragma unroll
    for (int e = 0; e < 4; ++e) a[e] += b[e];
    F4[idx] = a;
  }
  if (t < 100) msL[t] = ws[OFF_MP + n * 100 + t];
  else if (t < 200) mqL[t - 100] = ws[OFF_MP + (5 + q) * 100 + t - 100];
  __syncthreads();

  if (t < 100) {
    float s = 0.f;
    for (int ij = 0; ij < 100; ++ij) s += F[ij * 100 + t];
    float m = s * 0.01f;
    float ss = 0.f;
    for (int ij = 0; ij < 100; ++ij) { float d = F[ij * 100 + t] - m; ss += d * d; }
    float inv = 1.f / (sqrtf(ss * (1.f / 99.f) + 1e-5f) * 5.f);
    float den = 0.f;
    for (int ij = 0; ij < 100; ++ij) den += __expf((F[ij * 100 + t] - m) * inv);
    mc[t] = m; ic[t] = inv; rc[t] = 1.f / den;
  } else if (t < 200) {
    const int r = t - 100;
    float s = 0.f;
    for (int kl = 0; kl < 100; ++kl) s += F[r * 100 + kl];
    float m = s * 0.01f;
    float ss = 0.f;
    for (int kl = 0; kl < 100; ++kl) { float d = F[r * 100 + kl] - m; ss += d * d; }
    float inv = 1.f / (sqrtf(ss * (1.f / 99.f) + 1e-5f) * 5.f);
    float den = 0.f;
    for (int kl = 0; kl < 100; ++kl) den += __expf((F[r * 100 + kl] - m) * inv);
    mr[r] = m; ir[r] = inv; rr[r] = 1.f / den;
  }
  __syncthreads();
  if (t < 100) {
    float s = 0.f;
    for (int kl = 0; kl < 100; ++kl)
      s += __expf((F[t * 100 + kl] - mc[kl]) * ic[kl]) * rc[kl];
    asL[t] = s;
  } else if (t < 200) {
    const int r = t - 100;
    float s2 = 0.f;
    for (int ij = 0; ij < 100; ++ij)
      s2 += __expf((F[ij * 100 + r] - mr[ij]) * ir[ij]) * rr[ij];
    aqL[r] = s2;
  }
  __syncthreads();
  if (t < 2) {
    float s = 0.f;
    for (int p = 0; p < 100; ++p) s += t ? (aqL[p] * mqL[p]) : (asL[p] * msL[p]);
    alph[t] = s;
  }
  __syncthreads();

  const unsigned int* xs = (const unsigned int*)(ws + OFF_XTS + n * 32000);
  const unsigned int* xq = (const unsigned int*)(ws + OFF_XTQ + q * 32000);
  const float als = alph[0], alq = alph[1];
  float dot = 0.f, na = 0.f, nb = 0.f;
  for (int u = t; u < 320; u += 256) {
    float s0 = 0.f, s1 = 0.f, q0 = 0.f, q1 = 0.f;
    for (int p = 0; p < 100; ++p) {
      union { unsigned int u; fp16x2 h; } a, bq;
      a.u = xs[p * 320 + u];
      bq.u = xq[p * 320 + u];
      float ap = asL[p], qp = aqL[p];
      s0 += ap * (float)a.h[0]; s1 += ap * (float)a.h[1];
      q0 += qp * (float)bq.h[0]; q1 += qp * (float)bq.h[1];
    }
    float sa0 = (s0 - als) * 0.01f, sa1 = (s1 - als) * 0.01f;
    float qa0 = (q0 - alq) * 0.01f, qa1 = (q1 - alq) * 0.01f;
    dot += sa0 * qa0 + sa1 * qa1;
    na  += sa0 * sa0 + sa1 * sa1;
    nb  += qa0 * qa0 + qa1 * qa1;
  }
  #pragma unroll
  for (int off = 32; off > 0; off >>= 1) {
    dot += __shfl_down(dot, off);
    na  += __shfl_down(na, off);
    nb  += __shfl_down(nb, off);
  }
  const int wid = t >> 6, lanei = t & 63;
  if (lanei == 0) { red[wid * 3 + 0] = dot; red[wid * 3 + 1] = na; red[wid * 3 + 2] = nb; }
  __syncthreads();
  if (t == 0) {
    dot = red[0] + red[3] + red[6] + red[9];
    na  = red[1] + red[4] + red[7] + red[10];
    nb  = red[2] + red[5] + red[8] + red[11];
    float ns = sqrtf(na); ns = ns > 1e-8f ? ns : 1e-8f;
    float nq2 = sqrtf(nb); nq2 = nq2 > 1e-8f ? nq2 : 1e-8f;
    out[it] = dot / (ns * nq2) * 5.f;   // /TEMPERATURE(0.2)
  }
}

// ---------------------------------------------------------------------------
extern "C" void kernel_launch(void* const* d_in, const int* in_sizes, int n_in,
                              void* d_out, int out_size, void* d_ws, size_t ws_size,
                              hipStream_t stream)
{
  (void)in_sizes; (void)n_in; (void)out_size; (void)ws_size;
  const float* spt    = (const float*)d_in[0];
  const float* qry    = (const float*)d_in[1];
  const float* w1x1   = (const float*)d_in[2];
  const float* bn1x1  = (const float*)d_in[3];
  const float* c1c2w  = (const float*)d_in[4];
  const float* c1bn2  = (const float*)d_in[5];
  const float* c1c1w  = (const float*)d_in[6];
  const float* c1bn1  = (const float*)d_in[7];
  const float* c1pj   = (const float*)d_in[8];
  const float* c1bnp  = (const float*)d_in[9];
  const float* c2c2w  = (const float*)d_in[10];
  const float* c2bn2  = (const float*)d_in[11];
  const float* c2c1w  = (const float*)d_in[12];
  const float* c2bn1  = (const float*)d_in[13];
  const float* c2pj   = (const float*)d_in[14];
  const float* c2bnp  = (const float*)d_in[15];
  float* ws  = (float*)d_ws;
  float* out = (float*)d_out;

  k_prep<<<65, 256, 0, stream>>>(w1x1, bn1x1,
                                 c1c2w, c1bn2, c1c1w, c1bn1, c1pj, c1bnp,
                                 c2c2w, c2bn2, c2c1w, c2bn1, c2pj, c2bnp,
                                 ws + OFF_PRM);
  k_feat<<<80, 512, 0, stream>>>(spt, qry, ws, out);

  (void)hipFuncSetAttribute((const void*)k_cca,
                            hipFuncAttributeMaxDynamicSharedMemorySize, LDS_TOTAL5);
  k_cca<<<NITEM * 2, 1024, LDS_TOTAL5, stream>>>(ws);

  k_post<<<NITEM, 256, 0, stream>>>(ws, out);
}

// Round 7
// 310.837 us; speedup vs baseline: 1.0975x; 1.0975x over previous
//
#include <hip/hip_runtime.h>

// ---------------------------------------------------------------------------
// CCALayer: spt (1,5,640,10,10)  qry (75,640,10,10)
// Q=75, way=5, C=640, Cf=64, P=100 (10x10), items=375
// Output: sim (75,5) [375] ++ qry_pooled (75,640) [48000]
// ---------------------------------------------------------------------------

#define NITEM 375

// ws layout (float offsets)
#define OFF_XTS 0            // raw support transposed fp16 [5][100 p][640 c]
#define OFF_XTQ 160000       // raw query transposed fp16 [75][100][640]
#define OFF_MP  2560000      // per-image position means [80][100] f32
#define OFF_SF  2568000      // support feature MFMA frags fp16 [5][14336B]
#define OFF_QF  2600000      // query feature MFMA frags fp16 [75][14336B]
#define OFF_RA  3080000      // branch-A result 375*10000
#define OFF_RB  6830000      // branch-B result 375*10000
#define OFF_PRM 10655000     // folded params

// prm layout (floats):
// [0..143] W1eff[ds][i]; [144..159] Av; [160..175] Bp
// [176..191] S2c2; [192..207] B2c2
// [208..216] w2c1; [217..225] w1c1
// [226] S2 [227] B2 [228] S1 [229] B1 [230] Cf
// PK2 (conv2 A-frags, 2560 fp16) at floats [232,1512)
// PK1 (conv1eff A-frags, 2560 fp16) at floats [1512,2792)
// WSUM [2792,2856) ; SCV [2856,2920) ; SHV [2920,2984)
// PKW (feat GEMM A-frags, 51200 fp16) at floats [2984,28584)
#define PK2F 232
#define PK1F 1512
#define WSUMF 2792
#define SCVF 2856
#define SHVF 2920
#define PKWF 2984

// k_cca LDS byte map (dynamic, 161536 total)
//   [0,20480)        T2h
//   [20480,129280)   Y1 region, INTERLEAVED 32B entries (16ch fp16/entry):
//                    4 zero gaps (3200B) + 3 slots (32000B):
//                    gap r at 20480 + r*35200; slot s at 23680 + s*35200.
//   ZPB3 = 20480     zero page for masked loop-2 reads (inside gap0)
//   [129280,161536)  Y2, interleaved 32B entries x 1008
//   overlays (dead before main loop):
//     T1@20480   [f(100)][s1(10)][12] f32 = 48000B  -> [20480,68480)
//     CORR@71680 [f(100)][s1(10)][12] f32 = 48000B  -> [71680,119680)
#define Y1SLOT0  23680
#define Y1GAP3   3200
#define Y1SSTR3  35200
#define ZPB3     20480
#define Y2S3     129280
#define LDS_TOTAL3 161536

typedef float f4v __attribute__((ext_vector_type(4)));
typedef float f32x4 __attribute__((ext_vector_type(4)));
typedef _Float16 half8v __attribute__((ext_vector_type(8)));
typedef __fp16 fp16x2 __attribute__((ext_vector_type(2)));
typedef unsigned int u32x4 __attribute__((ext_vector_type(4)));
typedef unsigned int u32x2 __attribute__((ext_vector_type(2)));

__device__ __forceinline__ unsigned int pkrtz(float a, float b) {
  union { fp16x2 h; unsigned int u; } cv;
  cv.h = __builtin_amdgcn_cvt_pkrtz(a, b);
  return cv.u;
}

// ---------------------------------------------------------------------------
__global__ __launch_bounds__(256) void k_prep(
    const float* __restrict__ w1x1,  const float* __restrict__ bn1x1,
    const float* __restrict__ c1c2w, const float* __restrict__ c1bn2,
    const float* __restrict__ c1c1w, const float* __restrict__ c1bn1,
    const float* __restrict__ c1pj,  const float* __restrict__ c1bnp,
    const float* __restrict__ c2c2w, const float* __restrict__ c2bn2,
    const float* __restrict__ c2c1w, const float* __restrict__ c2bn1,
    const float* __restrict__ c2pj,  const float* __restrict__ c2bnp,
    float* __restrict__ prm)
{
  (void)w1x1; (void)bn1x1;
  const int t = threadIdx.x;
  const float eps = 1e-5f;

  for (int idx = t; idx < 144; idx += 256) {
    int ds = idx / 16, i = idx % 16;
    float spv = c2bnp[0] / sqrtf(c2bnp[3] + eps);
    float acc = 0.f;
    for (int o = 0; o < 16; ++o) {
      float s1 = c2bn1[o] / sqrtf(c2bn1[48 + o] + eps);
      acc += c2pj[o] * s1 * c2c1w[(o * 16 + i) * 9 + ds];
    }
    prm[idx] = spv * acc;
  }
  for (int i = t; i < 16; i += 256) {
    float s = c1bnp[i] / sqrtf(c1bnp[48 + i] + eps);
    prm[144 + i] = s * c1pj[i];
    prm[160 + i] = c1bnp[16 + i] - c1bnp[32 + i] * s;
  }
  for (int o = t; o < 16; o += 256) {
    float s = c2bn2[o] / sqrtf(c2bn2[48 + o] + eps);
    prm[176 + o] = s;
    prm[192 + o] = c2bn2[16 + o] - c2bn2[32 + o] * s;
  }
  for (int k = t; k < 9; k += 256) {
    prm[208 + k] = c1c2w[k];
    prm[217 + k] = c1c1w[k];
  }
  if (t == 0) {
    float S2 = c1bn2[0] / sqrtf(c1bn2[3] + eps);
    prm[226] = S2;
    prm[227] = c1bn2[1] - c1bn2[2] * S2;
    float S1 = c1bn1[0] / sqrtf(c1bn1[3] + eps);
    prm[228] = S1;
    prm[229] = c1bn1[1] - c1bn1[2] * S1;
    float spv = c2bnp[0] / sqrtf(c2bnp[3] + eps);
    float k0 = 0.f;
    for (int o = 0; o < 16; ++o) {
      float s1 = c2bn1[o] / sqrtf(c2bn1[48 + o] + eps);
      k0 += c2pj[o] * (c2bn1[16 + o] - c2bn1[32 + o] * s1);
    }
    prm[230] = spv * (k0 - c2bnp[2]) + c2bnp[1];
    prm[231] = 0.f;
  }
  __syncthreads();

  _Float16* pk2 = (_Float16*)(prm + PK2F);
  for (int idx = t; idx < 2560; idx += 256) {
    int c = idx >> 9, rem = idx & 511;
    int ln = rem >> 3, j = rem & 7;
    int o = ln & 15, qq = ln >> 4;
    int tap = 2 * c + (qq >> 1);
    int i = (qq & 1) * 8 + j;
    float v = (tap < 9) ? c2c2w[(o * 16 + i) * 9 + tap] : 0.f;
    pk2[idx] = (_Float16)v;
  }
  _Float16* pk1 = (_Float16*)(prm + PK1F);
  for (int idx = t; idx < 2560; idx += 256) {
    int c = idx >> 9, rem = idx & 511;
    int ln = rem >> 3, j = rem & 7;
    int m = ln & 15, qq = ln >> 4;
    int k = c * 32 + qq * 8 + j;
    int tp = k >> 4, i = k & 15;
    float v = (m == 0 && tp < 9) ? prm[tp * 16 + i] : 0.f;
    pk1[idx] = (_Float16)v;
  }
}

// ---------------------------------------------------------------------------
// PKW packing + per-o WSUM/SCV/SHV. grid = 64 blocks.
__global__ __launch_bounds__(256) void k_prepw(
    const float* __restrict__ w1x1, const float* __restrict__ bn1x1,
    float* __restrict__ prm)
{
  __shared__ float red[4];
  _Float16* pkw = (_Float16*)(prm + PKWF);
  const int t = threadIdx.x;
  const int base = blockIdx.x * 800;
  for (int r = t; r < 800; r += 256) {
    int idx = base + r;
    int fi = idx >> 9, rem = idx & 511;
    int ln = rem >> 3, j = rem & 7;
    int cc = fi / 10, r2 = fi - cc * 10;
    int mt = r2 >> 1, kk = r2 & 1;
    int m = mt * 16 + (ln & 15);
    int k = cc * 64 + kk * 32 + ((ln >> 4) & 3) * 8 + j;
    float v = (m < 64) ? w1x1[m * 640 + k] : (m == 64 ? 1.f : 0.f);
    pkw[idx] = (_Float16)v;
  }
  const int o = blockIdx.x;
  float s = 0.f;
  for (int c = t; c < 640; c += 256) s += w1x1[o * 640 + c];
  #pragma unroll
  for (int off = 32; off > 0; off >>= 1) s += __shfl_down(s, off);
  if ((t & 63) == 0) red[t >> 6] = s;
  __syncthreads();
  if (t == 0) {
    prm[WSUMF + o] = red[0] + red[1] + red[2] + red[3];
    float scv = bn1x1[o] / sqrtf(bn1x1[192 + o] + 1e-5f);
    prm[SCVF + o] = scv;
    prm[SHVF + o] = bn1x1[64 + o] - bn1x1[128 + o] * scv;
  }
}

// ---------------------------------------------------------------------------
// Fused center + 1x1 conv (MFMA) + BN + relu + L2 norm + XT emit + qry_pooled.
// R8: emits normalized features as fp16 MFMA fragments (consumed by k_cca's
// corr MFMA); f32 sf/qf emission removed.
__global__ __launch_bounds__(512) void k_feat(
    const float* __restrict__ spt, const float* __restrict__ qry,
    float* __restrict__ ws, float* __restrict__ out)
{
  __shared__ __align__(16) char POOL[2 * 16128];   // XTL[2]; OUT overlays
  __shared__ __align__(16) float mrow[112];
  __shared__ __align__(16) float rn[112];
  __shared__ float CS[2][512];
  __shared__ float RS[640];
  __shared__ float msumL;

  const int b = blockIdx.x, t = threadIdx.x;
  const int lane = t & 63, wvv = t >> 6;             // 8 waves
  const int n0 = lane & 15, qd = (lane >> 4) & 3;
  const float* src = (b < 5) ? spt + b * 64000 : qry + (b - 5) * 64000;
  unsigned int* xtg = (unsigned int*)(ws + ((b < 5) ? (OFF_XTS + b * 32000)
                                                    : (OFF_XTQ + (b - 5) * 32000)));
  const float* prm = ws + OFF_PRM;
  const _Float16* pkw = (const _Float16*)(prm + PKWF);

  // zero pad rows p=100..111 of both buffers
  for (int idx = t; idx < 864; idx += 512) {
    int bsel = idx / 432, r = idx - bsel * 432;
    ((unsigned int*)(POOL + bsel * 16128 + 100 * 144))[r] = 0u;
  }
  // prologue: stage cc=0 into buffer 0
  for (int u = t; u < 800; u += 512) {
    int cp = u / 25, p4 = u - cp * 25;
    const float* r0 = src + (2 * cp) * 100 + p4 * 4;
    f4v a = *(const f4v*)r0;
    f4v c1 = *(const f4v*)(r0 + 100);
    #pragma unroll
    for (int e = 0; e < 4; ++e)
      *(unsigned int*)((_Float16*)POOL + (p4 * 4 + e) * 72 + 2 * cp) = pkrtz(a[e], c1[e]);
  }
  __syncthreads();

  const int chp = t >> 3, part = t & 7;
  const int pLo = part * 13, pHi = (pLo + 13 < 100) ? pLo + 13 : 100;

  f32x4 acc[5];
  #pragma unroll
  for (int ti = 0; ti < 5; ++ti) { acc[ti][0]=0.f; acc[ti][1]=0.f; acc[ti][2]=0.f; acc[ti][3]=0.f; }

  for (int cc = 0; cc < 10; ++cc) {
    const int cur = cc & 1;
    const _Float16* Xc = (const _Float16*)(POOL + cur * 16128);
    _Float16* Xn = (_Float16*)(POOL + (cur ^ 1) * 16128);

    f4v pa[2], pc[2];
    if (cc < 9) {
      #pragma unroll
      for (int k = 0; k < 2; ++k) {
        int u = t + k * 512;
        if (u < 800) {
          int cp = u / 25, p4 = u - cp * 25;
          const float* r0 = src + ((cc + 1) * 64 + 2 * cp) * 100 + p4 * 4;
          pa[k] = *(const f4v*)r0;
          pc[k] = *(const f4v*)(r0 + 100);
        }
      }
    }
    for (int u = t; u < 3200; u += 512) {
      int p = u >> 5, cp = u & 31;
      xtg[p * 320 + cc * 32 + cp] = *(const unsigned int*)(Xc + p * 72 + 2 * cp);
    }
    #pragma unroll
    for (int kk = 0; kk < 2; ++kk) {
      #pragma unroll
      for (int ti = 0; ti < 5; ++ti) {
        int idx = wvv + ti * 8; if (idx > 34) idx = 34;
        int mt = idx / 7, nt = idx - mt * 7;
        half8v av = *(const half8v*)(pkw + (cc * 10 + mt * 2 + kk) * 512 + lane * 8);
        half8v bv = *(const half8v*)(Xc + (nt * 16 + n0) * 72 + kk * 32 + qd * 8);
        acc[ti] = __builtin_amdgcn_mfma_f32_16x16x32_f16(av, bv, acc[ti], 0, 0, 0);
      }
    }
    {
      float s = 0.f;
      for (int p = pLo; p < pHi; ++p) s += (float)Xc[p * 72 + chp];
      CS[cur][t] = s;
    }
    if (cc < 9) {
      #pragma unroll
      for (int k = 0; k < 2; ++k) {
        int u = t + k * 512;
        if (u < 800) {
          int cp = u / 25, p4 = u - cp * 25;
          #pragma unroll
          for (int e = 0; e < 4; ++e)
            *(unsigned int*)(Xn + (p4 * 4 + e) * 72 + 2 * cp) = pkrtz(pa[k][e], pc[k][e]);
        }
      }
    }
    __syncthreads();
    if (t < 64) {
      float s = 0.f;
      #pragma unroll
      for (int k = 0; k < 8; ++k) s += CS[cur][t * 8 + k];
      RS[cc * 64 + t] = s;
    }
  }
  #pragma unroll
  for (int ti = 0; ti < 5; ++ti) {
    int idx = wvv + ti * 8; if (idx > 34) idx = 34;
    int mt = idx / 7, nt = idx - mt * 7;
    if (mt == 4 && qd == 0) {
      int p = nt * 16 + n0;
      mrow[p] = acc[ti][0] * (1.f / 640.f);
    }
  }
  __syncthreads();
  float* OUT = (float*)POOL;                 // overlay: XTL dead from here
  if (t == 0) { float s = 0.f; for (int p = 0; p < 100; ++p) s += mrow[p]; msumL = s; }
  #pragma unroll
  for (int ti = 0; ti < 5; ++ti) {
    int idx = wvv + ti * 8; if (idx > 34) idx = 34;
    int mt = idx / 7, nt = idx - mt * 7;
    if (mt < 4) {
      int p = nt * 16 + n0;
      if (p < 100) {
        float mp = mrow[p];
        #pragma unroll
        for (int r = 0; r < 4; ++r) {
          int o = mt * 16 + qd * 4 + r;
          float v = acc[ti][r] - prm[WSUMF + o] * mp;
          v = prm[SCVF + o] * v + prm[SHVF + o];
          OUT[o * 104 + p] = v > 0.f ? v : 0.f;
        }
      }
    }
  }
  __syncthreads();
  if (t < 100) {
    float s = 0.f;
    for (int o = 0; o < 64; ++o) { float v = OUT[o * 104 + t]; s += v * v; }
    float nr = sqrtf(s);
    rn[t] = 1.f / (nr > 1e-8f ? nr : 1e-8f);
    ws[OFF_MP + b * 100 + t] = mrow[t];
  }
  __syncthreads();
  // Emit normalized features as fp16 MFMA fragments:
  // frag fi = kk*7 + pt ; u32 idx = fi*256 + lane*4 + jj
  // value[j=2jj+e] = feat[c = kk*32 + qd*8 + j][pos = pt*16 + n0] * rn[pos]
  {
    unsigned int* fg = (unsigned int*)((b < 5) ? (ws + OFF_SF) : (ws + OFF_QF))
                       + ((b < 5) ? b : (b - 5)) * 3584;
    for (int idx = t; idx < 3584; idx += 512) {
      const int jj = idx & 3;
      const int ln2 = (idx >> 2) & 63;
      const int fi = idx >> 8;
      const int kk = fi / 7, pt = fi - kk * 7;
      const int pos = pt * 16 + (ln2 & 15);
      const int c0 = kk * 32 + ((ln2 >> 4) & 3) * 8 + 2 * jj;
      float a = 0.f, bb = 0.f;
      if (pos < 100) {
        const float rv = rn[pos];
        a = OUT[c0 * 104 + pos] * rv;
        bb = OUT[(c0 + 1) * 104 + pos] * rv;
      }
      fg[idx] = pkrtz(a, bb);
    }
  }
  if (b >= 5) {
    const float msum = msumL;
    for (int gc = t; gc < 640; gc += 512)
      out[375 + (b - 5) * 640 + gc] = (RS[gc] - msum) * 0.01f;
  }
}

// ---------------------------------------------------------------------------
// Fused corr + cca branch. grid = 375 items x 2 branches.
// R8: corr via MFMA on prebuilt fp16 frags (br=1 = A/B role swap);
// CORR/T1 re-laid [f][s1][12] so all conv reads are aligned ds_read_b128;
// conv2-stage register-blocked over f1 (3x fewer LDS reads).
__global__ __launch_bounds__(1024) __attribute__((amdgpu_waves_per_eu(4, 4)))
void k_cca(float* __restrict__ ws)
{
  extern __shared__ char smem[];
  _Float16* T2h = (_Float16*)smem;
  float* T1   = (float*)(smem + 20480);
  float* CORR = (float*)(smem + 71680);

  const float* prm = ws + OFF_PRM;
  const int bid = blockIdx.x;
  const int it = bid >> 1, br = bid & 1;
  const int q = it / 5, n = it % 5;
  const int t = threadIdx.x;
  const int lane = t & 63, wv = t >> 6;
  const int n0 = lane & 15, qd = (lane >> 4) & 3;
  const int qh = qd >> 1, ih = qd & 1;

  const _Float16* pk2 = (const _Float16*)(prm + PK2F);
  const _Float16* pk1 = (const _Float16*)(prm + PK1F);
  half8v A2[5], A1[5];
  #pragma unroll
  for (int c = 0; c < 5; ++c) {
    A2[c] = *(const half8v*)(pk2 + c * 512 + lane * 8);
    A1[c] = *(const half8v*)(pk1 + c * 512 + lane * 8);
  }
  float sc2[4], bc2[4];
  #pragma unroll
  for (int r = 0; r < 4; ++r) { sc2[r] = prm[176 + qd * 4 + r]; bc2[r] = prm[192 + qd * 4 + r]; }

  const int d1E[5] = {-1,-1, 0, 0, 1}, d2E[5] = {-1, 1, 0,-1, 1};
  const int d1O[5] = {-1, 0, 0, 1, 0}, d2O[5] = { 0,-1, 1, 0, 0};

  // ---- g-invariant per-tile precompute ----
  int pp1[4], st1[4], addr2[4][5], posB[4];
  bool pv[4];
  #pragma unroll
  for (int ti = 0; ti < 4; ++ti) {
    int tile = wv + ti * 16; if (tile > 62) tile = 62;
    const int p = tile * 16 + n0;
    const int pcp = p < 1000 ? p : 999;
    pp1[ti] = pcp * 32 + ih * 16;
    st1[ti] = Y2S3 + p * 32 + qh * 16 + ih * 8;
    pv[ti] = (qd == 0) && (p < 1000);
    const int f2 = pcp / 100;
    const int s = pcp - f2 * 100;
    const int s1 = s / 10, s2 = s - s1 * 10;
    const bool rm = s1 > 0, rp = s1 < 9, cm = s2 > 0, cp2 = s2 < 9;
    const int b0 = Y2S3 + pcp * 32 + ih * 16;
    #pragma unroll
    for (int c = 0; c < 5; ++c) {
      const bool vE = (d1E[c] < 0 ? rm : (d1E[c] > 0 ? rp : true)) &&
                      (d2E[c] < 0 ? cm : (d2E[c] > 0 ? cp2 : true));
      const bool vO = (c == 4) ? false :
                      ((d1O[c] < 0 ? rm : (d1O[c] > 0 ? rp : true)) &&
                       (d2O[c] < 0 ? cm : (d2O[c] > 0 ? cp2 : true)));
      const bool v = qh ? vO : vE;
      const int D1c = (qh ? (d1O[c] * 10 + d2O[c]) : (d1E[c] * 10 + d2E[c]));
      addr2[ti][c] = v ? (b0 + D1c * 32) : ZPB3;
    }
    posB[ti] = br ? (s * 100 + f2) : (f2 * 100 + s);
  }
  const int posStride = br ? 10 : 1000;

  // ---- phase B: corr via MFMA from fp16 frags in global (L2-hot) ----
  {
    const half8v* fS = (const half8v*)(ws + OFF_SF) + n * 896;
    const half8v* fQ = (const half8v*)(ws + OFF_QF) + q * 896;
    const half8v* FA = br ? fQ : fS;   // rows (conv-f axis)
    const half8v* FB = br ? fS : fQ;   // cols (s axis)
    #pragma unroll
    for (int ti = 0; ti < 4; ++ti) {
      int T = wv + ti * 16; if (T > 48) T = 48;
      const int mt = T / 7, nt = T - mt * 7;
      half8v a0 = FA[mt * 64 + lane];
      half8v b0 = FB[nt * 64 + lane];
      half8v a1 = FA[(7 + mt) * 64 + lane];
      half8v b1 = FB[(7 + nt) * 64 + lane];
      f32x4 acc; acc[0]=0.f; acc[1]=0.f; acc[2]=0.f; acc[3]=0.f;
      acc = __builtin_amdgcn_mfma_f32_16x16x32_f16(a0, b0, acc, 0, 0, 0);
      acc = __builtin_amdgcn_mfma_f32_16x16x32_f16(a1, b1, acc, 0, 0, 0);
      const int s = nt * 16 + n0;
      if (s < 100) {
        const int s1a = s / 10;
        float* cp0 = CORR + s1a * 12 + (s - s1a * 10);
        const int r0 = mt * 16 + qd * 4;
        #pragma unroll
        for (int r = 0; r < 4; ++r)
          if (r0 + r < 100) cp0[(r0 + r) * 120] = acc[r];
      }
    }
  }
  __syncthreads();

  const float S2 = prm[226], B2 = prm[227], S1 = prm[228], B1 = prm[229];

  // ---- phase C: conv2-stage (3x3 over f), register-blocked over f1 ----
  if (t < 600) {
    const int h = t / 300, r2 = t - h * 300;
    const int f2 = r2 / 30, r3 = r2 - f2 * 30;
    const int s1v = r3 / 3, s2q = r3 - s1v * 3;
    const int cb = s1v * 12 + s2q * 4;
    f4v outv[5];
    #pragma unroll
    for (int i = 0; i < 5; ++i) { outv[i][0]=0.f; outv[i][1]=0.f; outv[i][2]=0.f; outv[i][3]=0.f; }
    #pragma unroll
    for (int k = 0; k < 7; ++k) {
      const int nf1 = 5 * h - 1 + k;
      if ((unsigned)nf1 >= 10u) continue;
      #pragma unroll
      for (int dv = 0; dv < 3; ++dv) {
        const int nf2 = f2 + dv - 1;
        if ((unsigned)nf2 >= 10u) continue;
        f4v x = *(const f4v*)(CORR + (nf1 * 10 + nf2) * 120 + cb);
        #pragma unroll
        for (int du = 0; du < 3; ++du) {
          const int f1l = k - du;                    // compile-time index
          if (f1l < 0 || f1l > 4) continue;
          const float w = prm[208 + du * 3 + dv];
          #pragma unroll
          for (int e = 0; e < 4; ++e) outv[f1l][e] += w * x[e];
        }
      }
    }
    #pragma unroll
    for (int f1l = 0; f1l < 5; ++f1l) {
      const int f = (5 * h + f1l) * 10 + f2;
      f4v v;
      #pragma unroll
      for (int e = 0; e < 4; ++e) { float z = S2 * outv[f1l][e] + B2; v[e] = z > 0.f ? z : 0.f; }
      *(f4v*)(T1 + f * 120 + cb) = v;
    }
  }
  __syncthreads();

  // ---- phase D: conv1-stage (3x3 over s) per f-row; T1 rows 48B-aligned ----
  if (t < 1000) {
    const int f = t / 10, s1 = t - (t / 10) * 10;
    const float* rowB = T1 + f * 120;
    f4v r[3][3];
    float w[3][3];
    #pragma unroll
    for (int dh = 0; dh < 3; ++dh) {
      int rr = s1 + dh - 1;
      bool okr = (unsigned)rr < 10u;
      int rc = rr < 0 ? 0 : (rr > 9 ? 9 : rr);
      const float* rp = rowB + rc * 12;
      r[dh][0] = *(const f4v*)(rp);
      r[dh][1] = *(const f4v*)(rp + 4);
      r[dh][2] = *(const f4v*)(rp + 8);
      #pragma unroll
      for (int dw = 0; dw < 3; ++dw) w[dh][dw] = okr ? prm[217 + dh * 3 + dw] : 0.f;
    }
    float o[10];
    #pragma unroll
    for (int s2 = 0; s2 < 10; ++s2) {
      float a = 0.f;
      #pragma unroll
      for (int dh = 0; dh < 3; ++dh)
        #pragma unroll
        for (int dw = 0; dw < 3; ++dw) {
          int col = s2 + dw - 1;
          if (col < 0 || col > 9) continue;
          a += w[dh][dw] * r[dh][col >> 2][col & 3];
        }
      o[s2] = a;
    }
    unsigned int* dst = (unsigned int*)((char*)T2h + (f * 100 + s1 * 10) * 2);
    #pragma unroll
    for (int k = 0; k < 5; ++k)
      dst[k] = pkrtz(S1 * o[2 * k] + B1, S1 * o[2 * k + 1] + B1);
  }
  __syncthreads();

  // GEN_Y1: 16 channels packed into one 32B entry (lo: ch0-7, hi: ch8-15)
  #define GEN_Y1(F1N)                                                          \
    if (t < 1000) {                                                            \
      const int _sl = (F1N) % 3;                                               \
      const float t2 = (float)T2h[(F1N) * 1000 + t];                           \
      unsigned int d[8];                                                       \
      _Pragma("unroll")                                                        \
      for (int j = 0; j < 8; ++j) {                                            \
        float ya = fmaxf(prm[144 + 2 * j] * t2 + prm[160 + 2 * j], 0.f);       \
        float yb = fmaxf(prm[145 + 2 * j] * t2 + prm[161 + 2 * j], 0.f);       \
        d[j] = pkrtz(ya, yb);                                                  \
      }                                                                        \
      u32x4 lo, hi;                                                            \
      lo[0]=d[0]; lo[1]=d[1]; lo[2]=d[2]; lo[3]=d[3];                          \
      hi[0]=d[4]; hi[1]=d[5]; hi[2]=d[6]; hi[3]=d[7];                          \
      *(u32x4*)(smem + Y1SLOT0 + _sl * Y1SSTR3 + t * 32) = lo;                 \
      *(u32x4*)(smem + Y1SLOT0 + _sl * Y1SSTR3 + t * 32 + 16) = hi;            \
    }

  GEN_Y1(0)
  GEN_Y1(1)
  {
    u32x4 zz; zz[0] = 0u; zz[1] = 0u; zz[2] = 0u; zz[3] = 0u;
    // zero the 4 guard gaps (3200 B each; gap0 doubles as ZPB3)
    for (int idx = t; idx < 800; idx += 1024) {
      const int r = idx / 200;
      *(u32x4*)(smem + 20480 + r * Y1SSTR3 + (idx - r * 200) * 16) = zz;
    }
    // zero slot 2 interior (virtual row f1=-1)
    for (int idx = t; idx < 2000; idx += 1024)
      *(u32x4*)(smem + Y1SLOT0 + 2 * Y1SSTR3 + idx * 16) = zz;
  }
  __syncthreads();

  const float Cf = prm[230];
  float* resb = ws + (br ? OFF_RB : OFF_RA) + it * 10000;
  int gp = 0;

  for (int g = 0; g < 10; ++g) {
    const int o0 = (g % 3) * Y1SSTR3;
    const int oP = ((g + 1) % 3) * Y1SSTR3;
    const int oM = ((g + 2) % 3) * Y1SSTR3;
    int base1[5];
    #pragma unroll
    for (int c = 0; c < 5; ++c) {
      const int eb = (d1E[c] < 0 ? oM : (d1E[c] > 0 ? oP : o0)) + d2E[c] * 3200;
      const int ob = (d1O[c] < 0 ? oM : (d1O[c] > 0 ? oP : o0)) + d2O[c] * 3200;
      base1[c] = Y1SLOT0 + (qh ? ob : eb);
    }

    #pragma unroll
    for (int ti = 0; ti < 4; ++ti) {
      f32x4 acc; acc[0]=0.f; acc[1]=0.f; acc[2]=0.f; acc[3]=0.f;
      #pragma unroll
      for (int c = 0; c < 5; ++c) {
        half8v b = *(const half8v*)(smem + base1[c] + pp1[ti]);
        acc = __builtin_amdgcn_mfma_f32_16x16x32_f16(A2[c], b, acc, 0, 0, 0);
      }
      const float v0 = fmaxf(sc2[0] * acc[0] + bc2[0], 0.f);
      const float v1 = fmaxf(sc2[1] * acc[1] + bc2[1], 0.f);
      const float v2 = fmaxf(sc2[2] * acc[2] + bc2[2], 0.f);
      const float v3 = fmaxf(sc2[3] * acc[3] + bc2[3], 0.f);
      u32x2 wq; wq[0] = pkrtz(v0, v1); wq[1] = pkrtz(v2, v3);
      *(u32x2*)(smem + st1[ti]) = wq;
    }
    __syncthreads();

    #pragma unroll
    for (int ti = 0; ti < 4; ++ti) {
      f32x4 acc; acc[0]=0.f; acc[1]=0.f; acc[2]=0.f; acc[3]=0.f;
      #pragma unroll
      for (int c = 0; c < 5; ++c) {
        half8v b = *(const half8v*)(smem + addr2[ti][c]);
        acc = __builtin_amdgcn_mfma_f32_16x16x32_f16(A1[c], b, acc, 0, 0, 0);
      }
      if (pv[ti]) resb[posB[ti] + gp] = acc[0] + Cf;
    }
    if (g + 2 <= 9) { GEN_Y1(g + 2) }
    else if (g == 8) {
      // virtual row f1=10 -> zero slot 1 interior
      u32x4 zz; zz[0] = 0u; zz[1] = 0u; zz[2] = 0u; zz[3] = 0u;
      for (int idx = t; idx < 2000; idx += 1024)
        *(u32x4*)(smem + Y1SLOT0 + Y1SSTR3 + idx * 16) = zz;
    }
    gp += posStride;
    __syncthreads();
  }
  #undef GEN_Y1
}

// ---------------------------------------------------------------------------
// Fused stats (gaussian_normalize + softmax + attn sums) + attention pooling
// + cosine similarity. grid = 375 items.
__global__ __launch_bounds__(256) void k_post(float* __restrict__ ws,
                                              float* __restrict__ out)
{
  __shared__ float F[10000];
  __shared__ float mc[100], ic[100], rc[100];
  __shared__ float mr[100], ir[100], rr[100];
  __shared__ float asL[100], aqL[100], msL[100], mqL[100];
  __shared__ float alph[2];
  __shared__ float red[12];
  const int it = blockIdx.x, t = threadIdx.x;
  const int q = it / 5, n = it % 5;

  const f4v* ra4 = (const f4v*)(ws + OFF_RA + it * 10000);
  const f4v* rb4 = (const f4v*)(ws + OFF_RB + it * 10000);
  f4v* F4 = (f4v*)F;
  for (int idx = t; idx < 2500; idx += 256) {
    f4v a = ra4[idx], b = rb4[idx];
    #pragma unroll
    for (int e = 0; e < 4; ++e) a[e] += b[e];
    F4[idx] = a;
  }
  if (t < 100) msL[t] = ws[OFF_MP + n * 100 + t];
  else if (t < 200) mqL[t - 100] = ws[OFF_MP + (5 + q) * 100 + t - 100];
  __syncthreads();

  if (t < 100) {
    float s = 0.f;
    for (int ij = 0; ij < 100; ++ij) s += F[ij * 100 + t];
    float m = s * 0.01f;
    float ss = 0.f;
    for (int ij = 0; ij < 100; ++ij) { float d = F[ij * 100 + t] - m; ss += d * d; }
    float inv = 1.f / (sqrtf(ss * (1.f / 99.f) + 1e-5f) * 5.f);
    float den = 0.f;
    for (int ij = 0; ij < 100; ++ij) den += __expf((F[ij * 100 + t] - m) * inv);
    mc[t] = m; ic[t] = inv; rc[t] = 1.f / den;
  } else if (t < 200) {
    const int r = t - 100;
    float s = 0.f;
    for (int kl = 0; kl < 100; ++kl) s += F[r * 100 + kl];
    float m = s * 0.01f;
    float ss = 0.f;
    for (int kl = 0; kl < 100; ++kl) { float d = F[r * 100 + kl] - m; ss += d * d; }
    float inv = 1.f / (sqrtf(ss * (1.f / 99.f) + 1e-5f) * 5.f);
    float den = 0.f;
    for (int kl = 0; kl < 100; ++kl) den += __expf((F[r * 100 + kl] - m) * inv);
    mr[r] = m; ir[r] = inv; rr[r] = 1.f / den;
  }
  __syncthreads();
  if (t < 100) {
    float s = 0.f;
    for (int kl = 0; kl < 100; ++kl)
      s += __expf((F[t * 100 + kl] - mc[kl]) * ic[kl]) * rc[kl];
    asL[t] = s;
  } else if (t < 200) {
    const int r = t - 100;
    float s2 = 0.f;
    for (int ij = 0; ij < 100; ++ij)
      s2 += __expf((F[ij * 100 + r] - mr[ij]) * ir[ij]) * rr[ij];
    aqL[r] = s2;
  }
  __syncthreads();
  if (t < 2) {
    float s = 0.f;
    for (int p = 0; p < 100; ++p) s += t ? (aqL[p] * mqL[p]) : (asL[p] * msL[p]);
    alph[t] = s;
  }
  __syncthreads();

  const unsigned int* xs = (const unsigned int*)(ws + OFF_XTS + n * 32000);
  const unsigned int* xq = (const unsigned int*)(ws + OFF_XTQ + q * 32000);
  const float als = alph[0], alq = alph[1];
  float dot = 0.f, na = 0.f, nb = 0.f;
  for (int u = t; u < 320; u += 256) {
    float s0 = 0.f, s1 = 0.f, q0 = 0.f, q1 = 0.f;
    for (int p = 0; p < 100; ++p) {
      union { unsigned int u; fp16x2 h; } a, bq;
      a.u = xs[p * 320 + u];
      bq.u = xq[p * 320 + u];
      float ap = asL[p], qp = aqL[p];
      s0 += ap * (float)a.h[0]; s1 += ap * (float)a.h[1];
      q0 += qp * (float)bq.h[0]; q1 += qp * (float)bq.h[1];
    }
    float sa0 = (s0 - als) * 0.01f, sa1 = (s1 - als) * 0.01f;
    float qa0 = (q0 - alq) * 0.01f, qa1 = (q1 - alq) * 0.01f;
    dot += sa0 * qa0 + sa1 * qa1;
    na  += sa0 * sa0 + sa1 * sa1;
    nb  += qa0 * qa0 + qa1 * qa1;
  }
  #pragma unroll
  for (int off = 32; off > 0; off >>= 1) {
    dot += __shfl_down(dot, off);
    na  += __shfl_down(na, off);
    nb  += __shfl_down(nb, off);
  }
  const int wid = t >> 6, lanei = t & 63;
  if (lanei == 0) { red[wid * 3 + 0] = dot; red[wid * 3 + 1] = na; red[wid * 3 + 2] = nb; }
  __syncthreads();
  if (t == 0) {
    dot = red[0] + red[3] + red[6] + red[9];
    na  = red[1] + red[4] + red[7] + red[10];
    nb  = red[2] + red[5] + red[8] + red[11];
    float ns = sqrtf(na); ns = ns > 1e-8f ? ns : 1e-8f;
    float nq2 = sqrtf(nb); nq2 = nq2 > 1e-8f ? nq2 : 1e-8f;
    out[it] = dot / (ns * nq2) * 5.f;   // /TEMPERATURE(0.2)
  }
}

// ---------------------------------------------------------------------------
extern "C" void kernel_launch(void* const* d_in, const int* in_sizes, int n_in,
                              void* d_out, int out_size, void* d_ws, size_t ws_size,
                              hipStream_t stream)
{
  (void)in_sizes; (void)n_in; (void)out_size; (void)ws_size;
  const float* spt    = (const float*)d_in[0];
  const float* qry    = (const float*)d_in[1];
  const float* w1x1   = (const float*)d_in[2];
  const float* bn1x1  = (const float*)d_in[3];
  const float* c1c2w  = (const float*)d_in[4];
  const float* c1bn2  = (const float*)d_in[5];
  const float* c1c1w  = (const float*)d_in[6];
  const float* c1bn1  = (const float*)d_in[7];
  const float* c1pj   = (const float*)d_in[8];
  const float* c1bnp  = (const float*)d_in[9];
  const float* c2c2w  = (const float*)d_in[10];
  const float* c2bn2  = (const float*)d_in[11];
  const float* c2c1w  = (const float*)d_in[12];
  const float* c2bn1  = (const float*)d_in[13];
  const float* c2pj   = (const float*)d_in[14];
  const float* c2bnp  = (const float*)d_in[15];
  float* ws  = (float*)d_ws;
  float* out = (float*)d_out;

  k_prep<<<1, 256, 0, stream>>>(w1x1, bn1x1,
                                c1c2w, c1bn2, c1c1w, c1bn1, c1pj, c1bnp,
                                c2c2w, c2bn2, c2c1w, c2bn1, c2pj, c2bnp,
                                ws + OFF_PRM);
  k_prepw<<<64, 256, 0, stream>>>(w1x1, bn1x1, ws + OFF_PRM);
  k_feat<<<80, 512, 0, stream>>>(spt, qry, ws, out);

  (void)hipFuncSetAttribute((const void*)k_cca,
                            hipFuncAttributeMaxDynamicSharedMemorySize, LDS_TOTAL3);
  k_cca<<<NITEM * 2, 1024, LDS_TOTAL3, stream>>>(ws);

  k_post<<<NITEM, 256, 0, stream>>>(ws, out);
}